// Round 1
// baseline (311.931 us; speedup 1.0000x reference)
//
#include <hip/hip_runtime.h>

// Problem constants (match reference)
#define N1 8192
#define N2 8192
#define FM 256
#define FD 256
#define FOUT 128

// Workspace layout (floats):
//   [0,   256)  v_m = w_m @ a[:128]
//   [256, 512)  v_d = w_d @ a[128:]
//   [512, 512+8192)        s1
//   [512+8192, 512+16384)  s2

// --- Kernel 1: v_m[k] = sum_j w_m[k,j]*a[j];  v_d[k] = sum_j w_d[k,j]*a[128+j]
// 512 blocks x 64 threads; block b<256 -> v_m[b], else v_d[b-256].
__global__ void __launch_bounds__(64) compute_v(const float* __restrict__ w_m,
                                                const float* __restrict__ w_d,
                                                const float* __restrict__ a,
                                                float* __restrict__ ws) {
    int b = blockIdx.x;
    int t = threadIdx.x;
    const float* w;
    const float* av;
    float* dst;
    int k;
    if (b < 256) { w = w_m; av = a;       dst = ws;       k = b; }
    else         { w = w_d; av = a + 128; dst = ws + 256; k = b - 256; }
    // 128-wide dot: each lane takes 2 elements (coalesced).
    float p = w[k * FOUT + t] * av[t] + w[k * FOUT + 64 + t] * av[64 + t];
    #pragma unroll
    for (int o = 32; o > 0; o >>= 1) p += __shfl_xor(p, o, 64);
    if (t == 0) dst[k] = p;
}

// --- Kernel 2: s1[i] = sum_k (am0*m+am1*m1+am2*m2)[i,k] * v_m[k]  (and s2 likewise)
// 16384 blocks x 64 threads; one wave per row, 4 elems/lane via float4.
__global__ void __launch_bounds__(64) compute_s(const float* __restrict__ m0,
                                                const float* __restrict__ m1,
                                                const float* __restrict__ m2,
                                                const float* __restrict__ d0,
                                                const float* __restrict__ d1,
                                                const float* __restrict__ d2,
                                                const float* __restrict__ am,
                                                const float* __restrict__ ad,
                                                const float* __restrict__ v,  // ws: v_m at 0, v_d at 256
                                                float* __restrict__ s) {      // s1 at 0, s2 at 8192
    int b = blockIdx.x;
    int t = threadIdx.x;
    const float *p0, *p1, *p2, *cf, *vv;
    int i;
    if (b < N1) { p0 = m0; p1 = m1; p2 = m2; cf = am; vv = v;       i = b; }
    else        { p0 = d0; p1 = d1; p2 = d2; cf = ad; vv = v + 256; i = b - N1; }
    float c0 = cf[0], c1 = cf[1], c2 = cf[2];
    size_t base = (size_t)i * FM + t * 4;
    const float4 a0 = *(const float4*)(p0 + base);
    const float4 a1 = *(const float4*)(p1 + base);
    const float4 a2 = *(const float4*)(p2 + base);
    const float4 vq = *(const float4*)(vv + t * 4);
    float p = (c0 * a0.x + c1 * a1.x + c2 * a2.x) * vq.x
            + (c0 * a0.y + c1 * a1.y + c2 * a2.y) * vq.y
            + (c0 * a0.z + c1 * a1.z + c2 * a2.z) * vq.z
            + (c0 * a0.w + c1 * a1.w + c2 * a2.w) * vq.w;
    #pragma unroll
    for (int o = 32; o > 0; o >>= 1) p += __shfl_xor(p, o, 64);
    if (t == 0) s[b] = p;
}

// mish(x) = x * tanh(softplus(x)).
// With t = e^x, u = 1+t:  tanh(ln u) = (u^2-1)/(u^2+1) = (t^2+2t)/(t^2+2t+2).
// Clamp exp arg at 40: t^2 <= 5.5e34 stays in f32; for x>40 ratio == 1 to 1e-35,
// so mish(x) -> x exactly as required. For x << 0, t -> 0, ratio -> 0: mish -> 0.
__device__ __forceinline__ float mish_f(float x) {
    float t = __expf(fminf(x, 40.0f));
    float w = t * (t + 2.0f);                       // t^2 + 2t
    float r = __builtin_amdgcn_rcpf(w + 2.0f);      // v_rcp_f32, ~1 ulp
    return x * (w * r);                             // w*r <= 1: no overflow
}

// --- Kernel 3: e[i,j] = mish(s1[i] + s2[j]).  Write-bound: 256 MB f32.
// 65536 blocks x 256 threads; 8 blocks per row; each thread one float4.
__global__ void __launch_bounds__(256) compute_e(const float* __restrict__ s,  // s1 at 0, s2 at 8192
                                                 float* __restrict__ out) {
    int i = blockIdx.x >> 3;
    int j = ((blockIdx.x & 7) << 10) + (threadIdx.x << 2);
    float x = s[i];                    // uniform per block -> scalar load
    const float4 sv = *(const float4*)(s + N1 + j);
    float4 r;
    r.x = mish_f(x + sv.x);
    r.y = mish_f(x + sv.y);
    r.z = mish_f(x + sv.z);
    r.w = mish_f(x + sv.w);
    *(float4*)(out + (size_t)i * N2 + j) = r;
}

extern "C" void kernel_launch(void* const* d_in, const int* in_sizes, int n_in,
                              void* d_out, int out_size, void* d_ws, size_t ws_size,
                              hipStream_t stream) {
    const float* m   = (const float*)d_in[0];
    const float* m1  = (const float*)d_in[1];
    const float* m2  = (const float*)d_in[2];
    const float* d0  = (const float*)d_in[3];
    const float* d1  = (const float*)d_in[4];
    const float* d2  = (const float*)d_in[5];
    // d_in[6] = adj (unused by forward)
    const float* w_m = (const float*)d_in[7];
    const float* w_d = (const float*)d_in[8];
    const float* a_m = (const float*)d_in[9];
    const float* a_d = (const float*)d_in[10];
    const float* a   = (const float*)d_in[11];

    float* ws = (float*)d_ws;
    float* v  = ws;          // v_m[256] then v_d[256]
    float* s  = ws + 512;    // s1[8192] then s2[8192]
    float* out = (float*)d_out;

    compute_v<<<512, 64, 0, stream>>>(w_m, w_d, a, ws);
    compute_s<<<N1 + N2, 64, 0, stream>>>(m, m1, m2, d0, d1, d2, a_m, a_d, v, s);
    compute_e<<<(N1 * (N2 / 4)) / 256, 256, 0, stream>>>(s, out);
}